// Round 1
// baseline (541.655 us; speedup 1.0000x reference)
//
#include <hip/hip_runtime.h>
#include <hip/hip_bf16.h>
#include <math.h>

#define B_ 16
#define D_ 768
#define N_ 1024
#define Z_ 256
#define TOPK_ 512
#define HW_ 32
#define EPS_ 1e-5f
#define BM_ 16

// ---------------- k_pre1: transpose conv_w; db = conv_b + conv_w@bp; bg = conv_b + conv_w@mask_token
__global__ __launch_bounds__(256) void k_pre1(const float* __restrict__ conv_w,
                                              const float* __restrict__ conv_b,
                                              const float* __restrict__ bp,
                                              const float* __restrict__ mtk,
                                              float* __restrict__ cwT,
                                              float* __restrict__ db,
                                              float* __restrict__ bg) {
  int tid = threadIdx.x;
  if (blockIdx.x < Z_) {
    int z = blockIdx.x;
    cwT[z * Z_ + tid] = conv_w[tid * Z_ + z];
  } else {
    float a1 = 0.f, a2 = 0.f;
    for (int z = 0; z < Z_; ++z) {
      float c = conv_w[tid * Z_ + z];
      a1 += c * bp[z];
      a2 += c * mtk[z];
    }
    db[tid] = conv_b[tid] + a1;
    bg[tid] = conv_b[tid] + a2;
  }
}

// ---------------- k_mt: Mt[d][o] = sum_z wp[d][z] * conv_w[o][z]  (fused wp·conv^T)
__global__ __launch_bounds__(256) void k_mt(const float* __restrict__ wp,
                                            const float* __restrict__ cwT,
                                            float* __restrict__ Mt) {
  int tid = threadIdx.x;
  int d0 = blockIdx.x * 8;
  float acc[8];
#pragma unroll
  for (int j = 0; j < 8; ++j) acc[j] = 0.f;
  for (int z = 0; z < Z_; ++z) {
    float c = cwT[z * Z_ + tid];
#pragma unroll
    for (int j = 0; j < 8; ++j) acc[j] += wp[(d0 + j) * Z_ + z] * c;
  }
#pragma unroll
  for (int j = 0; j < 8; ++j) Mt[(d0 + j) * Z_ + tid] = acc[j];
}

// ---------------- k_score: fused  score = sigmoid(relu(x@w1+b1)@w2+b2)  + LN stats
// grid: 16 batches * 64 tiles of 16 tokens. 256 threads; thread owns e=tid, tid+256, tid+512.
__global__ __launch_bounds__(256) void k_score(const float* __restrict__ xin,
                                               const float* __restrict__ w1,
                                               const float* __restrict__ b1,
                                               const float* __restrict__ w2,
                                               const float* __restrict__ b2,
                                               float* __restrict__ score,
                                               float* __restrict__ rs_out,   // scale slot (rsqrt var)
                                               float* __restrict__ mu_out) { // shift slot (mean)
  __shared__ float xs[D_ * BM_];     // 48 KB, [d][t]
  __shared__ float sred[4][BM_];
  int tid = threadIdx.x;
  int b = blockIdx.x >> 6;
  int n0 = (blockIdx.x & 63) * BM_;
  const float* xb = xin + (size_t)b * D_ * N_ + n0;
  // stage x tile: 768*16 floats, float4 loads (coalesced over n)
#pragma unroll
  for (int it = 0; it < 12; ++it) {
    int i4 = it * 256 + tid;
    int d = i4 >> 2, t4 = (i4 & 3) * 4;
    float4 v = *reinterpret_cast<const float4*>(xb + (size_t)d * N_ + t4);
    *reinterpret_cast<float4*>(&xs[d * BM_ + t4]) = v;
  }
  __syncthreads();
  // LayerNorm stats for later use (wave 0 lanes 0..15, one token each; bank-conflict-free)
  if (tid < BM_) {
    float s = 0.f, s2 = 0.f;
    for (int d = 0; d < D_; ++d) {
      float v = xs[d * BM_ + tid];
      s += v; s2 += v * v;
    }
    float m = s * (1.f / D_);
    float var = s2 * (1.f / D_) - m * m;
    mu_out[b * N_ + n0 + tid] = m;
    rs_out[b * N_ + n0 + tid] = rsqrtf(var + EPS_);
  }
  // main GEMM: acc[e-slot][token]
  float acc0[BM_], acc1[BM_], acc2[BM_];
#pragma unroll
  for (int t = 0; t < BM_; ++t) { acc0[t] = 0.f; acc1[t] = 0.f; acc2[t] = 0.f; }
  const float* w1p = w1 + tid;
  for (int d = 0; d < D_; ++d) {
    float wa = w1p[(size_t)d * D_];
    float wb = w1p[(size_t)d * D_ + 256];
    float wc = w1p[(size_t)d * D_ + 512];
#pragma unroll
    for (int q = 0; q < 4; ++q) {
      float4 xv = *reinterpret_cast<const float4*>(&xs[d * BM_ + q * 4]);
      acc0[q*4+0] += xv.x * wa; acc1[q*4+0] += xv.x * wb; acc2[q*4+0] += xv.x * wc;
      acc0[q*4+1] += xv.y * wa; acc1[q*4+1] += xv.y * wb; acc2[q*4+1] += xv.y * wc;
      acc0[q*4+2] += xv.z * wa; acc1[q*4+2] += xv.z * wb; acc2[q*4+2] += xv.z * wc;
      acc0[q*4+3] += xv.w * wa; acc1[q*4+3] += xv.w * wb; acc2[q*4+3] += xv.w * wc;
    }
  }
  float b1a = b1[tid], b1b = b1[tid + 256], b1c = b1[tid + 512];
  float w2a = w2[tid], w2b = w2[tid + 256], w2c = w2[tid + 512];
  float sp[BM_];
#pragma unroll
  for (int t = 0; t < BM_; ++t) {
    sp[t] = fmaxf(acc0[t] + b1a, 0.f) * w2a
          + fmaxf(acc1[t] + b1b, 0.f) * w2b
          + fmaxf(acc2[t] + b1c, 0.f) * w2c;
  }
#pragma unroll
  for (int off = 32; off > 0; off >>= 1) {
#pragma unroll
    for (int t = 0; t < BM_; ++t) sp[t] += __shfl_xor(sp[t], off, 64);
  }
  if ((tid & 63) == 0) {
    int w = tid >> 6;
#pragma unroll
    for (int t = 0; t < BM_; ++t) sred[w][t] = sp[t];
  }
  __syncthreads();
  if (tid < BM_) {
    float v = sred[0][tid] + sred[1][tid] + sred[2][tid] + sred[3][tid] + b2[0];
    score[b * N_ + n0 + tid] = 1.f / (1.f + expf(-v));
  }
}

// ---------------- k_select: exact rank per token (argsort(-s) stable semantics),
// per-token scale/shift for LN*score fusion, per-batch min/max.
// grid: 16 batches * 4 token-groups; 1024 threads; 4 threads cooperate per token (j-range split).
__global__ __launch_bounds__(1024) void k_select(const float* __restrict__ score,
                                                 float* __restrict__ scale_io, // in: rs, out: rs*score
                                                 float* __restrict__ shift_io, // in: mu, out: -mu*rs*score
                                                 int* __restrict__ rank,
                                                 float* __restrict__ mm) {
  __shared__ float s[N_];
  __shared__ float red[32];
  int tid = threadIdx.x;
  int b = blockIdx.x >> 2;
  int tg = blockIdx.x & 3;
  s[tid] = score[b * N_ + tid];
  __syncthreads();
  int token = tg * 256 + (tid >> 2);
  int jq = tid & 3;
  float si = s[token];
  int cnt = 0;
  int j0 = jq * 256;
  for (int j = j0; j < j0 + 256; j += 4) {
    float4 sj = *reinterpret_cast<const float4*>(&s[j]);
    cnt += (sj.x > si) || (sj.x == si && (j + 0) < token);
    cnt += (sj.y > si) || (sj.y == si && (j + 1) < token);
    cnt += (sj.z > si) || (sj.z == si && (j + 2) < token);
    cnt += (sj.w > si) || (sj.w == si && (j + 3) < token);
  }
  cnt += __shfl_xor(cnt, 1, 64);
  cnt += __shfl_xor(cnt, 2, 64);
  if (jq == 0) {
    rank[b * N_ + token] = cnt;
    float sc = scale_io[b * N_ + token] * si;
    float sh = -shift_io[b * N_ + token] * sc;
    scale_io[b * N_ + token] = sc;
    shift_io[b * N_ + token] = sh;
  }
  if (tg == 0) {
    float v = s[tid];
    float mn = v, mx = v;
#pragma unroll
    for (int off = 32; off > 0; off >>= 1) {
      mn = fminf(mn, __shfl_xor(mn, off, 64));
      mx = fmaxf(mx, __shfl_xor(mx, off, 64));
    }
    if ((tid & 63) == 0) { red[tid >> 6] = mn; red[16 + (tid >> 6)] = mx; }
    __syncthreads();
    if (tid == 0) {
      float a = red[0], c = red[16];
      for (int w = 1; w < 16; ++w) { a = fminf(a, red[w]); c = fmaxf(c, red[16 + w]); }
      mm[2 * b] = a; mm[2 * b + 1] = c;
    }
  }
}

// ---------------- k_gather: gt[b][d][rank] = x[b][d][n]*scale[n] + shift[n]  for selected n
__global__ __launch_bounds__(256) void k_gather(const float* __restrict__ xin,
                                                const float* __restrict__ scale,
                                                const float* __restrict__ shiftv,
                                                const int* __restrict__ rank,
                                                float* __restrict__ gt) {
  int tid = threadIdx.x;
  int b = blockIdx.x / 96;
  int d0 = (blockIdx.x % 96) * 8;
  int rk[4]; float sc[4], sh[4];
#pragma unroll
  for (int r = 0; r < 4; ++r) {
    int n = r * 256 + tid;
    rk[r] = rank[b * N_ + n];
    sc[r] = scale[b * N_ + n];
    sh[r] = shiftv[b * N_ + n];
  }
  for (int dd = 0; dd < 8; ++dd) {
    int d = d0 + dd;
    const float* xr = xin + ((size_t)(b * D_ + d)) * N_;
    float* gr = gt + ((size_t)(b * D_ + d)) * TOPK_;
#pragma unroll
    for (int r = 0; r < 4; ++r) {
      int n = r * 256 + tid;
      float v = xr[n];
      if (rk[r] < TOPK_) gr[rk[r]] = v * sc[r] + sh[r];
    }
  }
}

// ---------------- k_gemm2: dec_sel[b][k][o] = db[o] + sum_d gt[b][d][k] * Mt[d][o]
// grid: 16 b * 16 k-tiles of 32; 256 threads, thread owns o=tid.
__global__ __launch_bounds__(256) void k_gemm2(const float* __restrict__ gt,
                                               const float* __restrict__ Mt,
                                               const float* __restrict__ db,
                                               float* __restrict__ dsel) {
  __shared__ float gs[D_ * 32];   // 96 KB
  int tid = threadIdx.x;
  int b = blockIdx.x >> 4;
  int k0 = (blockIdx.x & 15) * 32;
  const float* gb = gt + ((size_t)b * D_) * TOPK_ + k0;
#pragma unroll
  for (int it = 0; it < 24; ++it) {
    int i4 = it * 256 + tid;
    int d = i4 >> 3, t4 = (i4 & 7) * 4;
    float4 v = *reinterpret_cast<const float4*>(gb + (size_t)d * TOPK_ + t4);
    *reinterpret_cast<float4*>(&gs[d * 32 + t4]) = v;
  }
  __syncthreads();
  float acc[32];
#pragma unroll
  for (int t = 0; t < 32; ++t) acc[t] = 0.f;
  for (int d = 0; d < D_; ++d) {
    float w = Mt[d * Z_ + tid];
#pragma unroll
    for (int q = 0; q < 8; ++q) {
      float4 g4 = *reinterpret_cast<const float4*>(&gs[d * 32 + q * 4]);
      acc[q*4+0] += g4.x * w; acc[q*4+1] += g4.y * w;
      acc[q*4+2] += g4.z * w; acc[q*4+3] += g4.w * w;
    }
  }
  float dbv = db[tid];
#pragma unroll
  for (int t = 0; t < 32; ++t)
    dsel[((size_t)b * TOPK_ + k0 + t) * Z_ + tid] = acc[t] + dbv;
}

// ---------------- k_dec: scatter dec_sel / background into dec output (coalesced over n)
__global__ __launch_bounds__(256) void k_dec(const float* __restrict__ dsel,
                                             const float* __restrict__ bg,
                                             const int* __restrict__ rank,
                                             float* __restrict__ out) {
  int tid = threadIdx.x;
  int b = blockIdx.x >> 8;
  int o = blockIdx.x & 255;
  float bgv = bg[o];
  float* orow = out + ((size_t)(b * Z_ + o)) * N_;
#pragma unroll
  for (int r = 0; r < 4; ++r) {
    int n = r * 256 + tid;
    int rk = rank[b * N_ + n];
    float v = (rk < TOPK_) ? dsel[((size_t)b * TOPK_ + rk) * Z_ + o] : bgv;
    orow[n] = v;
  }
}

// ---------------- k_maps: binary_map + score_map (nearest upsample x16), float4 stores
__global__ __launch_bounds__(128) void k_maps(const float* __restrict__ score,
                                              const int* __restrict__ rank,
                                              const float* __restrict__ mm,
                                              float* __restrict__ out) {
  int tid = threadIdx.x;
  int b = blockIdx.x >> 9;
  int ph = blockIdx.x & 511;
  float mn = mm[0], mx = mm[1];
#pragma unroll
  for (int w = 1; w < 16; ++w) { mn = fminf(mn, mm[2 * w]); mx = fmaxf(mx, mm[2 * w + 1]); }
  float inv = 1.f / fmaxf(mx - mn, EPS_);
  int pw0 = tid * 4;
  int cell = (ph >> 4) * HW_ + (pw0 >> 4);
  int rk = rank[b * N_ + cell];
  float bin = (rk < TOPK_) ? 1.f : 0.f;
  float sv = (score[b * N_ + cell] - mn) * inv;
  size_t base = (size_t)b * (512 * 512) + (size_t)ph * 512 + pw0;
  float4 bv = {bin, bin, bin, bin};
  float4 svv = {sv, sv, sv, sv};
  *reinterpret_cast<float4*>(out + 4194304 + base) = bv;
  *reinterpret_cast<float4*>(out + 8388608 + base) = svv;
}

extern "C" void kernel_launch(void* const* d_in, const int* in_sizes, int n_in,
                              void* d_out, int out_size, void* d_ws, size_t ws_size,
                              hipStream_t stream) {
  const float* xin = (const float*)d_in[0];
  const float* w1  = (const float*)d_in[1];
  const float* b1  = (const float*)d_in[2];
  const float* w2  = (const float*)d_in[3];
  const float* b2  = (const float*)d_in[4];
  const float* wp  = (const float*)d_in[5];
  const float* bp  = (const float*)d_in[6];
  const float* mtk = (const float*)d_in[7];
  const float* cw  = (const float*)d_in[8];
  const float* cb  = (const float*)d_in[9];
  float* out = (float*)d_out;

  float* ws     = (float*)d_ws;
  float* Mt     = ws;                    // 196608
  float* cwT    = Mt + 196608;           // 65536
  float* db     = cwT + 65536;           // 256
  float* bg     = db + 256;              // 256
  float* score  = bg + 256;              // 16384
  float* scalev = score + 16384;         // 16384 (rs -> rs*score)
  float* shiftv = scalev + 16384;        // 16384 (mu -> -mu*rs*score)
  int*   rank   = (int*)(shiftv + 16384);// 16384
  float* mm     = (float*)(rank + 16384);// 32
  float* gt     = mm + 32;               // 6291456
  float* dsel   = gt + 6291456;          // 2097152
  // total ~34.9 MB of d_ws

  k_pre1 <<<dim3(257),  dim3(256),  0, stream>>>(cw, cb, bp, mtk, cwT, db, bg);
  k_mt   <<<dim3(96),   dim3(256),  0, stream>>>(wp, cwT, Mt);
  k_score<<<dim3(1024), dim3(256),  0, stream>>>(xin, w1, b1, w2, b2, score, scalev, shiftv);
  k_select<<<dim3(64),  dim3(1024), 0, stream>>>(score, scalev, shiftv, rank, mm);
  k_gather<<<dim3(1536),dim3(256),  0, stream>>>(xin, scalev, shiftv, rank, gt);
  k_gemm2<<<dim3(256),  dim3(256),  0, stream>>>(gt, Mt, db, dsel);
  k_dec  <<<dim3(4096), dim3(256),  0, stream>>>(dsel, bg, rank, out);
  k_maps <<<dim3(8192), dim3(128),  0, stream>>>(score, rank, mm, out);
}

// Round 3
// 253.863 us; speedup vs baseline: 2.1337x; 2.1337x over previous
//
#include <hip/hip_runtime.h>
#include <hip/hip_bf16.h>
#include <math.h>

#define B_ 16
#define D_ 768
#define N_ 1024
#define Z_ 256
#define TOPK_ 512
#define HW_ 32
#define EPS_ 1e-5f

typedef unsigned int uint;
typedef unsigned short ushort;
typedef __attribute__((ext_vector_type(4))) short short4v;
typedef __attribute__((ext_vector_type(8))) short bf16x8;
typedef __attribute__((ext_vector_type(4))) float f32x4;
typedef __attribute__((ext_vector_type(4))) int int4v;

__device__ __forceinline__ ushort f2bf(float v) {
  uint b = __float_as_uint(v);
  b += 0x7FFFu + ((b >> 16) & 1u);
  return (ushort)(b >> 16);
}
__device__ __forceinline__ float bf2f(ushort h) { return __uint_as_float(((uint)h) << 16); }
__device__ __forceinline__ int pk2(ushort a, ushort b) { return (int)((uint)a | ((uint)b << 16)); }

// ---------------- k_pre1: db = conv_b + conv_w@bp; bg = conv_b + conv_w@mask_token
__global__ __launch_bounds__(256) void k_pre1(const float* __restrict__ conv_w,
                                              const float* __restrict__ conv_b,
                                              const float* __restrict__ bp,
                                              const float* __restrict__ mtk,
                                              float* __restrict__ db,
                                              float* __restrict__ bg) {
  int o = threadIdx.x;
  float a1 = 0.f, a2 = 0.f;
  for (int z = 0; z < Z_; ++z) {
    float c = conv_w[o * Z_ + z];
    a1 += c * bp[z];
    a2 += c * mtk[z];
  }
  db[o] = conv_b[o] + a1;
  bg[o] = conv_b[o] + a2;
}

// ---------------- k_w1pack: A-fragments of w1^T, hi/lo split bf16.
// frag f=(eg,kkg): lane l: e = eg*16+(l&15), slot j -> d = kkg*32 + 8*(l>>4) + j (contiguous k)
__global__ __launch_bounds__(64) void k_w1pack(const float* __restrict__ w1,
                                               short* __restrict__ wA) {
  int lane = threadIdx.x;
  int f = blockIdx.x;             // 48*24 = 1152
  int eg = f / 24, kkg = f % 24;
  int e = eg * 16 + (lane & 15);
  int d0 = kkg * 32 + 8 * (lane >> 4);
  ushort hh[8], ll[8];
#pragma unroll
  for (int j = 0; j < 8; ++j) {
    float v = w1[(size_t)(d0 + j) * D_ + e];
    hh[j] = f2bf(v);
    ll[j] = f2bf(v - bf2f(hh[j]));
  }
  int4v ph = {pk2(hh[0],hh[1]), pk2(hh[2],hh[3]), pk2(hh[4],hh[5]), pk2(hh[6],hh[7])};
  int4v pl = {pk2(ll[0],ll[1]), pk2(ll[2],ll[3]), pk2(ll[4],ll[5]), pk2(ll[6],ll[7])};
  int4v* W = (int4v*)wA;
  W[(size_t)f * 128 + lane] = ph;
  W[(size_t)f * 128 + 64 + lane] = pl;
}

// ---------------- k_mtpack: Mt[d][o] = sum_z wp[d][z]*conv_w[o][z], A-fragments (bf16, contiguous k)
__global__ __launch_bounds__(64) void k_mtpack(const float* __restrict__ wp,
                                               const float* __restrict__ conv_w,
                                               short* __restrict__ mtA) {
  int lane = threadIdx.x;
  int f = blockIdx.x;             // 16*24 = 384
  int og = f / 24, kkg = f % 24;
  int o = og * 16 + (lane & 15);
  int d0 = kkg * 32 + 8 * (lane >> 4);
  float acc[8] = {0.f,0.f,0.f,0.f,0.f,0.f,0.f,0.f};
  for (int z = 0; z < Z_; ++z) {
    float c = conv_w[o * Z_ + z];
#pragma unroll
    for (int j = 0; j < 8; ++j) acc[j] += wp[(size_t)(d0 + j) * Z_ + z] * c;
  }
  int4v p = {pk2(f2bf(acc[0]),f2bf(acc[1])), pk2(f2bf(acc[2]),f2bf(acc[3])),
             pk2(f2bf(acc[4]),f2bf(acc[5])), pk2(f2bf(acc[6]),f2bf(acc[7]))};
  ((int4v*)mtA)[(size_t)f * 64 + lane] = p;
}

// ---------------- k_score_mfma: score = sigmoid(relu(x@w1+b1)@w2+b2), split-bf16 MFMA
// 64 tokens/block, 512 thr = 8 waves; wave owns 96 e's (6 et), all 64 tokens (4 tn).
// LDS: [t][dloc^swz] bf16 hi/lo panels, chunked over d (KC=128).
__global__ __launch_bounds__(512, 2) void k_score_mfma(const float* __restrict__ xin,
                                                       const short* __restrict__ wA,
                                                       const float* __restrict__ b1,
                                                       const float* __restrict__ w2,
                                                       const float* __restrict__ b2,
                                                       float* __restrict__ score) {
  __shared__ short panH[64 * 128];
  __shared__ short panL[64 * 128];
  __shared__ float red[8][4][16];
  int tid = threadIdx.x;
  int wave = tid >> 6, lane = tid & 63;
  int g = lane >> 4, cc = lane & 15;
  int b = blockIdx.x >> 4;
  int n0 = (blockIdx.x & 15) * 64;
  const float* xb = xin + (size_t)b * D_ * N_ + n0;
  int qt = tid & 15, qd = tid >> 4;
  int t0 = qt * 4, dl0 = qd * 4;
  f32x4 acc[6][4];
#pragma unroll
  for (int et = 0; et < 6; ++et)
#pragma unroll
    for (int tn = 0; tn < 4; ++tn) acc[et][tn] = (f32x4){0.f,0.f,0.f,0.f};
  const int4v* Ab = (const int4v*)wA;
  for (int kc = 0; kc < 6; ++kc) {
    float4 v0 = *(const float4*)(xb + (size_t)(kc*128 + dl0 + 0) * N_ + t0);
    float4 v1 = *(const float4*)(xb + (size_t)(kc*128 + dl0 + 1) * N_ + t0);
    float4 v2 = *(const float4*)(xb + (size_t)(kc*128 + dl0 + 2) * N_ + t0);
    float4 v3 = *(const float4*)(xb + (size_t)(kc*128 + dl0 + 3) * N_ + t0);
    __syncthreads();   // previous chunk's compute done before overwrite
#define STG(j, e0, e1, e2, e3) { \
    int t = t0 + (j); \
    int sb = t * 128 + (dl0 ^ ((t & 7) << 3)); \
    ushort h0 = f2bf(e0), h1 = f2bf(e1), h2 = f2bf(e2), h3 = f2bf(e3); \
    short4v ph = {(short)h0,(short)h1,(short)h2,(short)h3}; \
    short4v pl = {(short)f2bf((e0)-bf2f(h0)), (short)f2bf((e1)-bf2f(h1)), \
                  (short)f2bf((e2)-bf2f(h2)), (short)f2bf((e3)-bf2f(h3))}; \
    *(short4v*)&panH[sb] = ph; \
    *(short4v*)&panL[sb] = pl; }
    STG(0, v0.x, v1.x, v2.x, v3.x)
    STG(1, v0.y, v1.y, v2.y, v3.y)
    STG(2, v0.z, v1.z, v2.z, v3.z)
    STG(3, v0.w, v1.w, v2.w, v3.w)
#undef STG
    __syncthreads();
#pragma unroll
    for (int kk = 0; kk < 4; ++kk) {
      bf16x8 Bh[4], Bl[4];
#pragma unroll
      for (int tn = 0; tn < 4; ++tn) {
        int t = tn * 16 + cc;
        int sb = t * 128 + ((kk * 32 + 8 * g) ^ ((t & 7) << 3));
        Bh[tn] = *(const bf16x8*)&panH[sb];
        Bl[tn] = *(const bf16x8*)&panL[sb];
      }
#pragma unroll
      for (int et = 0; et < 6; ++et) {
        size_t fidx = ((size_t)((wave * 6 + et) * 24 + (kc * 4 + kk))) * 128 + lane;
        union { int4v i; bf16x8 v; } ah, al;
        ah.i = Ab[fidx];
        al.i = Ab[fidx + 64];
#pragma unroll
        for (int tn = 0; tn < 4; ++tn) {
          acc[et][tn] = __builtin_amdgcn_mfma_f32_16x16x32_bf16(ah.v, Bh[tn], acc[et][tn], 0, 0, 0);
          acc[et][tn] = __builtin_amdgcn_mfma_f32_16x16x32_bf16(ah.v, Bl[tn], acc[et][tn], 0, 0, 0);
          acc[et][tn] = __builtin_amdgcn_mfma_f32_16x16x32_bf16(al.v, Bh[tn], acc[et][tn], 0, 0, 0);
        }
      }
    }
  }
  // epilogue: relu + dot(w2), reduce over e
  float lg[4] = {0.f,0.f,0.f,0.f};
#pragma unroll
  for (int et = 0; et < 6; ++et) {
    int e = wave * 96 + et * 16 + 4 * g;
    float4 bb = *(const float4*)(b1 + e);
    float4 ww = *(const float4*)(w2 + e);
#pragma unroll
    for (int tn = 0; tn < 4; ++tn) {
      lg[tn] += fmaxf(acc[et][tn][0] + bb.x, 0.f) * ww.x;
      lg[tn] += fmaxf(acc[et][tn][1] + bb.y, 0.f) * ww.y;
      lg[tn] += fmaxf(acc[et][tn][2] + bb.z, 0.f) * ww.z;
      lg[tn] += fmaxf(acc[et][tn][3] + bb.w, 0.f) * ww.w;
    }
  }
#pragma unroll
  for (int tn = 0; tn < 4; ++tn) {
    lg[tn] += __shfl_xor(lg[tn], 16, 64);
    lg[tn] += __shfl_xor(lg[tn], 32, 64);
  }
  if (lane < 16) {
#pragma unroll
    for (int tn = 0; tn < 4; ++tn) red[wave][tn][lane] = lg[tn];
  }
  __syncthreads();
  if (tid < 64) {
    float v = b2[0];
#pragma unroll
    for (int w = 0; w < 8; ++w) v += red[w][tid >> 4][tid & 15];
    score[b * N_ + n0 + tid] = 1.f / (1.f + expf(-v));
  }
}

// ---------------- k_select: exact rank (stable argsort(-s) semantics) + batch min/max
__global__ __launch_bounds__(1024) void k_select(const float* __restrict__ score,
                                                 int* __restrict__ rank,
                                                 float* __restrict__ mm) {
  __shared__ float s[N_];
  __shared__ float red[32];
  int tid = threadIdx.x;
  int b = blockIdx.x >> 2;
  int tg = blockIdx.x & 3;
  s[tid] = score[b * N_ + tid];
  __syncthreads();
  int token = tg * 256 + (tid >> 2);
  int jq = tid & 3;
  float si = s[token];
  int cnt = 0;
  int j0 = jq * 256;
  for (int j = j0; j < j0 + 256; j += 4) {
    float4 sj = *reinterpret_cast<const float4*>(&s[j]);
    cnt += (sj.x > si) || (sj.x == si && (j + 0) < token);
    cnt += (sj.y > si) || (sj.y == si && (j + 1) < token);
    cnt += (sj.z > si) || (sj.z == si && (j + 2) < token);
    cnt += (sj.w > si) || (sj.w == si && (j + 3) < token);
  }
  cnt += __shfl_xor(cnt, 1, 64);
  cnt += __shfl_xor(cnt, 2, 64);
  if (jq == 0) rank[b * N_ + token] = cnt;
  if (tg == 0) {
    float v = s[tid];
    float mn = v, mx = v;
#pragma unroll
    for (int off = 32; off > 0; off >>= 1) {
      mn = fminf(mn, __shfl_xor(mn, off, 64));
      mx = fmaxf(mx, __shfl_xor(mx, off, 64));
    }
    if ((tid & 63) == 0) { red[tid >> 6] = mn; red[16 + (tid >> 6)] = mx; }
    __syncthreads();
    if (tid == 0) {
      float a = red[0], c = red[16];
      for (int w = 1; w < 16; ++w) { a = fminf(a, red[w]); c = fmaxf(c, red[16 + w]); }
      mm[2 * b] = a; mm[2 * b + 1] = c;
    }
  }
}

// ---------------- k_gather_t: fused LN stats + normalize*score + transpose + rank-compact
// out: gtT[b][rank][d] bf16 (token-major rows)
__global__ __launch_bounds__(512) void k_gather_t(const float* __restrict__ xin,
                                                  const float* __restrict__ score,
                                                  const int* __restrict__ rank,
                                                  short* __restrict__ gtT) {
  __shared__ float pan[32][769];
  __shared__ float sw1[8][32], sw2[8][32];
  __shared__ float ssc[32], ssh[32];
  __shared__ int rkv[32];
  int tid = threadIdx.x;
  int b = blockIdx.x >> 5;
  int n0 = (blockIdx.x & 31) * 32;
  int qt = tid & 7, dbs = tid >> 3;
  const float* xb = xin + (size_t)b * D_ * N_ + n0 + qt * 4;
  float a0=0.f,a1=0.f,a2=0.f,a3=0.f,q0=0.f,q1=0.f,q2=0.f,q3=0.f;
#pragma unroll
  for (int it = 0; it < 12; ++it) {
    int d = it * 64 + dbs;
    float4 v = *(const float4*)(xb + (size_t)d * N_);
    pan[qt*4+0][d] = v.x; pan[qt*4+1][d] = v.y; pan[qt*4+2][d] = v.z; pan[qt*4+3][d] = v.w;
    a0 += v.x; q0 += v.x*v.x; a1 += v.y; q1 += v.y*v.y;
    a2 += v.z; q2 += v.z*v.z; a3 += v.w; q3 += v.w*v.w;
  }
#pragma unroll
  for (int m = 8; m <= 32; m <<= 1) {
    a0 += __shfl_xor(a0, m, 64); q0 += __shfl_xor(q0, m, 64);
    a1 += __shfl_xor(a1, m, 64); q1 += __shfl_xor(q1, m, 64);
    a2 += __shfl_xor(a2, m, 64); q2 += __shfl_xor(q2, m, 64);
    a3 += __shfl_xor(a3, m, 64); q3 += __shfl_xor(q3, m, 64);
  }
  int lane = tid & 63, wave = tid >> 6;
  if (lane < 8) {
    sw1[wave][lane*4+0] = a0; sw2[wave][lane*4+0] = q0;
    sw1[wave][lane*4+1] = a1; sw2[wave][lane*4+1] = q1;
    sw1[wave][lane*4+2] = a2; sw2[wave][lane*4+2] = q2;
    sw1[wave][lane*4+3] = a3; sw2[wave][lane*4+3] = q3;
  }
  __syncthreads();
  if (tid < 32) {
    float S = 0.f, Q = 0.f;
#pragma unroll
    for (int w = 0; w < 8; ++w) { S += sw1[w][tid]; Q += sw2[w][tid]; }
    float mu = S * (1.f / D_);
    float var = Q * (1.f / D_) - mu * mu;
    float rs = rsqrtf(var + EPS_);
    float sc = rs * score[b * N_ + n0 + tid];
    ssc[tid] = sc; ssh[tid] = -mu * sc;
    rkv[tid] = rank[b * N_ + n0 + tid];
  }
  __syncthreads();
  for (int t = 0; t < 32; ++t) {
    int rk = rkv[t];
    if (rk < TOPK_ && tid < 384) {
      float sc = ssc[t], sh = ssh[t];
      float u0 = pan[t][2*tid]   * sc + sh;
      float u1 = pan[t][2*tid+1] * sc + sh;
      ((uint*)(gtT + ((size_t)(b * TOPK_ + rk)) * D_))[tid] =
          (uint)f2bf(u0) | ((uint)f2bf(u1) << 16);
    }
  }
}

// ---------------- k_gemm2m: dselT[b][o][k] = db[o] + sum_d gtT[b][k][d]*Mt[d][o]  (bf16 MFMA)
__global__ __launch_bounds__(512, 2) void k_gemm2m(const short* __restrict__ gtT,
                                                   const short* __restrict__ mtA,
                                                   const float* __restrict__ db,
                                                   float* __restrict__ dselT) {
  __shared__ short pan[64 * 128];
  int tid = threadIdx.x;
  int wave = tid >> 6, lane = tid & 63;
  int g = lane >> 4, cc = lane & 15;
  int b = blockIdx.x >> 3, kt = blockIdx.x & 7;
  int srow = tid >> 3, scol = (tid & 7) * 16;
  const short* gb = gtT + (size_t)(b * TOPK_ + kt * 64) * D_;
  f32x4 acc[2][4];
#pragma unroll
  for (int et = 0; et < 2; ++et)
#pragma unroll
    for (int tn = 0; tn < 4; ++tn) acc[et][tn] = (f32x4){0.f,0.f,0.f,0.f};
  const int4v* Am = (const int4v*)mtA;
  for (int kc = 0; kc < 6; ++kc) {
    int4v u0 = *(const int4v*)(gb + (size_t)srow * D_ + kc*128 + scol);
    int4v u1 = *(const int4v*)(gb + (size_t)srow * D_ + kc*128 + scol + 8);
    __syncthreads();
    int sz = (srow & 7) << 3;
    *(int4v*)&pan[srow * 128 + (scol ^ sz)] = u0;
    *(int4v*)&pan[srow * 128 + ((scol + 8) ^ sz)] = u1;
    __syncthreads();
#pragma unroll
    for (int kk = 0; kk < 4; ++kk) {
      bf16x8 Bv[4];
#pragma unroll
      for (int tn = 0; tn < 4; ++tn) {
        int t = tn * 16 + cc;
        int sb = t * 128 + ((kk * 32 + 8 * g) ^ ((t & 7) << 3));
        Bv[tn] = *(const bf16x8*)&pan[sb];
      }
#pragma unroll
      for (int et = 0; et < 2; ++et) {
        size_t fidx = ((size_t)((wave * 2 + et) * 24 + (kc * 4 + kk))) * 64 + lane;
        union { int4v i; bf16x8 v; } av; av.i = Am[fidx];
#pragma unroll
        for (int tn = 0; tn < 4; ++tn)
          acc[et][tn] = __builtin_amdgcn_mfma_f32_16x16x32_bf16(av.v, Bv[tn], acc[et][tn], 0, 0, 0);
      }
    }
  }
#pragma unroll
  for (int et = 0; et < 2; ++et) {
    int o0 = wave * 32 + et * 16 + 4 * g;
#pragma unroll
    for (int r = 0; r < 4; ++r) {
      int o = o0 + r;
      float dbv = db[o];
      float* orow = dselT + ((size_t)(b * Z_ + o)) * TOPK_ + kt * 64 + cc;
      orow[0]  = acc[et][0][r] + dbv;
      orow[16] = acc[et][1][r] + dbv;
      orow[32] = acc[et][2][r] + dbv;
      orow[48] = acc[et][3][r] + dbv;
    }
  }
}

// ---------------- k_dec: dec[b][o][n] = selected ? dselT[b][o][rank[n]] : bg[o]
__global__ __launch_bounds__(256) void k_dec(const float* __restrict__ dselT,
                                             const float* __restrict__ bg,
                                             const int* __restrict__ rank,
                                             float* __restrict__ out) {
  __shared__ float row[TOPK_];
  __shared__ int rks[N_];
  int tid = threadIdx.x;
  int b = blockIdx.x >> 8;
  int o = blockIdx.x & 255;
  row[tid]       = dselT[((size_t)(b * Z_ + o)) * TOPK_ + tid];
  row[tid + 256] = dselT[((size_t)(b * Z_ + o)) * TOPK_ + tid + 256];
#pragma unroll
  for (int r = 0; r < 4; ++r) rks[r*256+tid] = rank[b * N_ + r*256 + tid];
  __syncthreads();
  float bgv = bg[o];
  float* orow = out + ((size_t)(b * Z_ + o)) * N_;
#pragma unroll
  for (int r = 0; r < 4; ++r) {
    int rk = rks[r*256+tid];
    orow[r*256+tid] = (rk < TOPK_) ? row[rk] : bgv;
  }
}

// ---------------- k_maps: binary_map + score_map (nearest upsample x16)
__global__ __launch_bounds__(128) void k_maps(const float* __restrict__ score,
                                              const int* __restrict__ rank,
                                              const float* __restrict__ mm,
                                              float* __restrict__ out) {
  int tid = threadIdx.x;
  int b = blockIdx.x >> 9;
  int ph = blockIdx.x & 511;
  float mn = mm[0], mx = mm[1];
#pragma unroll
  for (int w = 1; w < 16; ++w) { mn = fminf(mn, mm[2 * w]); mx = fmaxf(mx, mm[2 * w + 1]); }
  float inv = 1.f / fmaxf(mx - mn, EPS_);
  int pw0 = tid * 4;
  int cell = (ph >> 4) * HW_ + (pw0 >> 4);
  int rk = rank[b * N_ + cell];
  float bin = (rk < TOPK_) ? 1.f : 0.f;
  float sv = (score[b * N_ + cell] - mn) * inv;
  size_t base = (size_t)b * (512 * 512) + (size_t)ph * 512 + pw0;
  float4 bv = {bin, bin, bin, bin};
  float4 svv = {sv, sv, sv, sv};
  *reinterpret_cast<float4*>(out + 4194304 + base) = bv;
  *reinterpret_cast<float4*>(out + 8388608 + base) = svv;
}

extern "C" void kernel_launch(void* const* d_in, const int* in_sizes, int n_in,
                              void* d_out, int out_size, void* d_ws, size_t ws_size,
                              hipStream_t stream) {
  const float* xin = (const float*)d_in[0];
  const float* w1  = (const float*)d_in[1];
  const float* b1  = (const float*)d_in[2];
  const float* w2  = (const float*)d_in[3];
  const float* b2  = (const float*)d_in[4];
  const float* wp  = (const float*)d_in[5];
  const float* bp  = (const float*)d_in[6];
  const float* mtk = (const float*)d_in[7];
  const float* cw  = (const float*)d_in[8];
  const float* cb  = (const float*)d_in[9];
  float* out = (float*)d_out;

  short* wA   = (short*)d_ws;                 // 1,179,648 shorts
  short* mtA  = wA + 1179648;                 // 196,608 shorts
  short* gtT  = mtA + 196608;                 // 6,291,456 shorts
  float* db   = (float*)(gtT + 6291456);
  float* bg   = db + 256;
  float* score = bg + 256;
  float* mm   = score + 16384;
  int*   rank = (int*)(mm + 32);
  float* dselT = (float*)(rank + 16384);      // 2,097,152 floats
  // total ~23.9 MB

  k_pre1      <<<dim3(1),    dim3(256),  0, stream>>>(cw, cb, bp, mtk, db, bg);
  k_w1pack    <<<dim3(1152), dim3(64),   0, stream>>>(w1, wA);
  k_mtpack    <<<dim3(384),  dim3(64),   0, stream>>>(wp, cw, mtA);
  k_score_mfma<<<dim3(256),  dim3(512),  0, stream>>>(xin, wA, b1, w2, b2, score);
  k_select    <<<dim3(64),   dim3(1024), 0, stream>>>(score, rank, mm);
  k_gather_t  <<<dim3(512),  dim3(512),  0, stream>>>(xin, score, rank, gtT);
  k_gemm2m    <<<dim3(128),  dim3(512),  0, stream>>>(gtT, mtA, db, dselT);
  k_dec       <<<dim3(4096), dim3(256),  0, stream>>>(dselT, bg, rank, out);
  k_maps      <<<dim3(8192), dim3(128),  0, stream>>>(score, rank, mm, out);
}